// Round 1
// baseline (148.352 us; speedup 1.0000x reference)
//
#include <hip/hip_runtime.h>

#define TT 1024
#define LL 32
#define KK 128
#define CHUNK 4
#define NBLK (TT/CHUNK)   // 256 blocks

// d_ws layout (in floats):
#define ALPHA0_OFF 0                         // 32 floats: alpha0 = Ms[0][0][:]
#define PATH_OFF   32                        // 256 floats: per-block path partials
#define P0_OFF     288                       // 256 chunk-product matrices (1024 floats each)
#define P1_OFF     (P0_OFF + NBLK*1024)      // 64 matrices
#define P2_OFF     (P1_OFF + 64*1024)        // 16 matrices
#define P3_OFF     (P2_OFF + 16*1024)        // 4 matrices
#define P4_OFF     (P3_OFF + 4*1024)         // 1 matrix (final product of Ms[1..1023])

// One output cell of a 32x32x32 log-sum-exp semiring matmul:
// C[i][j] = max_k(A[i][k]+B[k][j]) + log(sum_k exp(...-max))
__device__ __forceinline__ float lse_cell(const float A[LL][LL+1],
                                          const float B[LL][LL+1],
                                          int i, int j) {
  float s[LL];
  #pragma unroll
  for (int k = 0; k < LL; k++) s[k] = A[i][k] + B[k][j];
  float mx = s[0];
  #pragma unroll
  for (int k = 1; k < LL; k++) mx = fmaxf(mx, s[k]);
  float sum = 0.f;
  #pragma unroll
  for (int k = 0; k < LL; k++) sum += __expf(s[k] - mx);
  return mx + __logf(sum);
}

// Stage A: each block computes Ms for CHUNK consecutive t, its path-score
// partial, and the lse-semiring product of its chunk's matrices.
__global__ __launch_bounds__(1024, 1) void crf_stageA(
    const float4* __restrict__ X4, const float* __restrict__ w,
    const int* __restrict__ label, float* __restrict__ ws) {
  __shared__ float Ms[CHUNK][LL][LL + 1];
  __shared__ float Pb[2][LL][LL + 1];
  const int blk = blockIdx.x, tid = threadIdx.x;
  const int l5 = tid & 31;            // lane within 32-group (covers K via float4)
  const int half = (tid >> 5) & 1;    // which half-wave
  const int wid = tid >> 6;           // wave id 0..15
  const int cellbase = wid * 2 + half; // 0..31: the (i*32+j)%32 slot this group owns
  const float4 w4 = reinterpret_cast<const float4*>(w)[l5];  // w[4*l5 .. 4*l5+3]
  const int t0 = blk * CHUNK;

  // ---- Ms computation: lanes-over-K, float4 loads, 32-lane shfl reduce ----
  #pragma unroll
  for (int m = 0; m < CHUNK; m++) {
    #pragma unroll 4
    for (int it = 0; it < LL; it++) {
      const int cell = it * LL + cellbase;          // i*32+j
      float4 xv = X4[(size_t)(t0 + m) * 1024u * 32u + (size_t)cell * 32u + l5];
      float v = xv.x * w4.x + xv.y * w4.y + xv.z * w4.z + xv.w * w4.w;
      v += __shfl_xor(v, 16, 32);
      v += __shfl_xor(v,  8, 32);
      v += __shfl_xor(v,  4, 32);
      v += __shfl_xor(v,  2, 32);
      v += __shfl_xor(v,  1, 32);
      if (l5 == 0) Ms[m][it][cellbase] = v;
    }
  }
  __syncthreads();

  // ---- path-score partial for this chunk ----
  if (tid == 0) {
    float ps = 0.f;
    for (int m = 0; m < CHUNK; m++) {
      const int t = t0 + m;
      const int lab = label[t];
      const int pv = (t == 0) ? 0 : label[t - 1];   // BEG = 0
      ps += Ms[m][pv][lab];
    }
    ws[PATH_OFF + blk] = ps;
  }
  // ---- alpha0 from the very first matrix ----
  if (blk == 0 && tid < LL) ws[ALPHA0_OFF + tid] = Ms[0][0][tid];

  // ---- chunk product: P = Ms[first] (x) Ms[first+1] (x) ... (x) Ms[CHUNK-1] ----
  const int i = tid >> 5, j = tid & 31;
  const int first = (blk == 0) ? 1 : 0;  // Ms[0] is alpha0's source, not in the product
  Pb[0][i][j] = lse_cell(Ms[first], Ms[first + 1], i, j);
  int cur = 0;
  for (int m = first + 2; m < CHUNK; m++) {
    __syncthreads();                     // Pb[cur] complete for all threads
    float r = lse_cell(Pb[cur], Ms[m], i, j);
    Pb[cur ^ 1][i][j] = r;
    cur ^= 1;
  }
  ws[P0_OFF + blk * 1024 + tid] = Pb[cur][i][j];   // thread reads its own write
}

// Tree combine: block b sequentially lse-multiplies `radix` consecutive
// source matrices (order-preserving) into one destination matrix.
__global__ __launch_bounds__(1024, 1) void crf_combine(
    const float* __restrict__ src, float* __restrict__ dst, int radix) {
  __shared__ float A[2][LL][LL + 1];
  __shared__ float Bm[LL][LL + 1];
  const int blk = blockIdx.x, tid = threadIdx.x;
  const int i = tid >> 5, j = tid & 31;
  const float* sp = src + (size_t)blk * radix * 1024;
  A[0][i][j] = sp[tid];
  int cur = 0;
  for (int r = 1; r < radix; r++) {
    __syncthreads();                     // prior iter's reads of Bm complete
    Bm[i][j] = sp[(size_t)r * 1024 + tid];
    __syncthreads();                     // Bm and A[cur] visible
    float v = lse_cell(A[cur], Bm, i, j);
    A[cur ^ 1][i][j] = v;
    cur ^= 1;
  }
  dst[(size_t)blk * 1024 + tid] = A[cur][i][j];    // own value, no barrier needed
}

// Final: logZ = lse_j( lse_i( alpha0[i] + P[i][j] ) ); out = -path + logZ
__global__ __launch_bounds__(256, 1) void crf_final(
    const float* __restrict__ ws, float* __restrict__ out) {
  __shared__ float Pf[LL][LL + 1];
  __shared__ float a0[LL];
  __shared__ float al[LL];
  __shared__ float red[4];
  const int tid = threadIdx.x;
  for (int idx = tid; idx < 1024; idx += 256) Pf[idx >> 5][idx & 31] = ws[P4_OFF + idx];
  if (tid < LL) a0[tid] = ws[ALPHA0_OFF + tid];
  // parallel sum of 256 path partials
  float ps = ws[PATH_OFF + tid];
  ps += __shfl_xor(ps, 32);
  ps += __shfl_xor(ps, 16);
  ps += __shfl_xor(ps,  8);
  ps += __shfl_xor(ps,  4);
  ps += __shfl_xor(ps,  2);
  ps += __shfl_xor(ps,  1);
  if ((tid & 63) == 0) red[tid >> 6] = ps;
  __syncthreads();
  if (tid < LL) {
    float s[LL];
    #pragma unroll
    for (int k = 0; k < LL; k++) s[k] = a0[k] + Pf[k][tid];
    float mx = s[0];
    #pragma unroll
    for (int k = 1; k < LL; k++) mx = fmaxf(mx, s[k]);
    float sum = 0.f;
    #pragma unroll
    for (int k = 0; k < LL; k++) sum += __expf(s[k] - mx);
    al[tid] = mx + __logf(sum);
  }
  __syncthreads();
  if (tid == 0) {
    float mx = al[0];
    for (int k = 1; k < LL; k++) mx = fmaxf(mx, al[k]);
    float sum = 0.f;
    for (int k = 0; k < LL; k++) sum += __expf(al[k] - mx);
    float logZ = mx + __logf(sum);
    float path = red[0] + red[1] + red[2] + red[3];
    out[0] = -path + logZ;
  }
}

extern "C" void kernel_launch(void* const* d_in, const int* in_sizes, int n_in,
                              void* d_out, int out_size, void* d_ws, size_t ws_size,
                              hipStream_t stream) {
  const float4* X4 = (const float4*)d_in[0];
  const float* w = (const float*)d_in[1];
  const int* label = (const int*)d_in[2];
  float* out = (float*)d_out;
  float* ws = (float*)d_ws;

  crf_stageA<<<NBLK, 1024, 0, stream>>>(X4, w, label, ws);
  crf_combine<<<64, 1024, 0, stream>>>(ws + P0_OFF, ws + P1_OFF, 4);  // 256 -> 64
  crf_combine<<<16, 1024, 0, stream>>>(ws + P1_OFF, ws + P2_OFF, 4);  //  64 -> 16
  crf_combine<<<4, 1024, 0, stream>>>(ws + P2_OFF, ws + P3_OFF, 4);   //  16 -> 4
  crf_combine<<<1, 1024, 0, stream>>>(ws + P3_OFF, ws + P4_OFF, 4);   //   4 -> 1
  crf_final<<<1, 256, 0, stream>>>(ws, out);
}